// Round 5
// baseline (462.301 us; speedup 1.0000x reference)
//
#include <hip/hip_runtime.h>
#include <hip/hip_bf16.h>

// LengthRegulator: out[b,t,:] = x[b, searchsorted_right(cum[b], t).clip(0,L-1), :]
//                  masked to 0 where t >= cum[b, L-1].
// B=32, L=1024, D=384, MAX_LEN=8192. fp32 in/out.
// Floor for OUR work: 403 MB nt-write + ~50 MB cold x read => ~85 us mixed.
// dur_us carries ~330 us of harness poison-fill/restore we cannot touch.
//
// R5: single fused kernel. Each block (96,4)=384 thr handles 128 output rows
// of one batch: redundant per-block LDS scan of the batch's 1024 durations
// (double-buffered Hillis-Steele; hides under co-resident blocks' stores),
// 128 binary searches, then nt-store copy with 2 rows in flight.
// Kills: 2nd launch, 32-CU scan serialization, ws idx round-trip.

#define B_FIXED 32
#define L_FIXED 1024
#define ROW_F4 96        // 384 floats / 4
#define RPB 128          // output rows per block

typedef float vfloat4 __attribute__((ext_vector_type(4)));

__global__ __launch_bounds__(384) void lr_fused_kernel(
    const float* __restrict__ durations, const vfloat4* __restrict__ x,
    vfloat4* __restrict__ out, int max_len) {
    __shared__ int sa[L_FIXED];
    __shared__ int sb[L_FIXED];
    __shared__ int s_idx[RPB];

    const int b = blockIdx.y;
    const int t0 = blockIdx.x * RPB;
    const int lin = threadIdx.y * 96 + threadIdx.x;

    // Phase 1: load + round/clip durations for this batch.
    for (int i = lin; i < L_FIXED; i += 384)
        sa[i] = (int)rintf(fmaxf(durations[b * L_FIXED + i], 0.0f));
    __syncthreads();

    // Phase 2: inclusive scan, double-buffered Hillis-Steele (no RAW hazard,
    // one barrier per level).
    int* src = sa;
    int* dst = sb;
    for (int off = 1; off < L_FIXED; off <<= 1) {
        for (int i = lin; i < L_FIXED; i += 384)
            dst[i] = src[i] + ((i >= off) ? src[i - off] : 0);
        __syncthreads();
        int* tmp = src; src = dst; dst = tmp;
    }
    const int total = src[L_FIXED - 1];

    // Phase 3: searchsorted_right for this block's 128 t values.
    if (lin < RPB) {
        const int t = t0 + lin;
        int lo = 0, hi = L_FIXED;
        while (lo < hi) {
            int mid = (lo + hi) >> 1;
            if (src[mid] <= t) lo = mid + 1; else hi = mid;
        }
        s_idx[lin] = (t < total) ? min(lo, L_FIXED - 1) : -1;
    }
    __syncthreads();

    // Phase 4: streaming gather-copy, 2 rows in flight, nontemporal stores.
    const long xbase = (long)b * L_FIXED * ROW_F4;
    const long obase = ((long)b * max_len + t0) * ROW_F4;
    const int cx = threadIdx.x;
    const int y  = threadIdx.y;
    const vfloat4 zero = {0.f, 0.f, 0.f, 0.f};

#pragma unroll
    for (int k = 0; k < RPB / 8; ++k) {      // 16 iterations
        const int ra = y + 8 * k;
        const int rb = ra + 4;
        const int rowa = s_idx[ra];
        const int rowb = s_idx[rb];
        vfloat4 va = zero, vb = zero;
        if (rowa >= 0) va = x[xbase + (long)rowa * ROW_F4 + cx];
        if (rowb >= 0) vb = x[xbase + (long)rowb * ROW_F4 + cx];
        __builtin_nontemporal_store(va, &out[obase + (long)ra * ROW_F4 + cx]);
        __builtin_nontemporal_store(vb, &out[obase + (long)rb * ROW_F4 + cx]);
    }
}

extern "C" void kernel_launch(void* const* d_in, const int* in_sizes, int n_in,
                              void* d_out, int out_size, void* d_ws, size_t ws_size,
                              hipStream_t stream) {
    const float* x = (const float*)d_in[0];          // (B, L, D) fp32
    const float* durations = (const float*)d_in[1];  // (B, L) fp32
    const int MAX_LEN = 8192;

    dim3 grid(MAX_LEN / RPB, B_FIXED);               // (64, 32) = 2048 blocks
    dim3 block(96, 4);
    lr_fused_kernel<<<grid, block, 0, stream>>>(
        durations, (const vfloat4*)x, (vfloat4*)d_out, MAX_LEN);
}